// Round 2
// baseline (238.653 us; speedup 1.0000x reference)
//
#include <hip/hip_runtime.h>
#include <hip/hip_bf16.h>
#include <stdint.h>

// ContrastiveLoss: sum over edges of -log( exp(pos)/ (exp(pos)+sum exp(neg)) + 1e-8 )
// with L2-normalized embeddings, temperature 0.5, and JAX-threefry negative sampling.
//
// JAX RNG replication notes (audited vs jax/_src/prng.py):
//  - jax.random.key(42) -> key data (0, 42)
//  - modern JAX (threefry_partitionable=True): split is fold-like:
//      k1 = threefry2x32((0,42), (0,0)), k2 = threefry2x32((0,42), (0,1))
//    random_bits(key, 32, shape)[i] = x0^x1 of threefry2x32(key, (0, i))
//  - randint: span=N-2=99998 > 2^16 => multiplier=rem(mul_u32(65536,65536),span)
//    where the mul wraps mod 2^32 => multiplier==0 => offset = lower_bits % span.
//    General formula kept (mult passed from host) in case span changes.
#define JAX_THREEFRY_PARTITIONABLE 1

struct U2 { uint32_t a, b; };

__host__ __device__ constexpr uint32_t rotl32(uint32_t v, int r) {
    return (v << r) | (v >> (32 - r));
}

__host__ __device__ constexpr U2 tf2x32(uint32_t k0, uint32_t k1, uint32_t x0, uint32_t x1) {
    const uint32_t ks2 = k0 ^ k1 ^ 0x1BD11BDAu;
    const uint32_t ks[3] = {k0, k1, ks2};
    const int rot[2][4] = {{13, 15, 26, 6}, {17, 29, 16, 24}};
    x0 += ks[0]; x1 += ks[1];
    #pragma unroll
    for (int j = 1; j <= 5; ++j) {
        const int* rr = rot[(j - 1) & 1];
        #pragma unroll
        for (int q = 0; q < 4; ++q) { x0 += x1; x1 = rotl32(x1, rr[q]); x1 ^= x0; }
        x0 += ks[j % 3];
        x1 += ks[(j + 1) % 3] + (uint32_t)j;
    }
    return {x0, x1};
}

#if JAX_THREEFRY_PARTITIONABLE
// fold-like split of key(42)=(0,42)
constexpr U2 KEY_HI = tf2x32(0u, 42u, 0u, 0u);  // k1 (higher bits key)
constexpr U2 KEY_LO = tf2x32(0u, 42u, 0u, 1u);  // k2 (lower bits key)
#else
// original split: counts iota(4)=[0,1,2,3]; pairs (0,2),(1,3)
constexpr U2 ENC02 = tf2x32(0u, 42u, 0u, 2u);
constexpr U2 ENC13 = tf2x32(0u, 42u, 1u, 3u);
constexpr U2 KEY_HI = {ENC02.a, ENC13.a};
constexpr U2 KEY_LO = {ENC02.b, ENC13.b};
#endif

__device__ __forceinline__ uint32_t draw_bits(uint32_t ka, uint32_t kb, uint32_t i, uint32_t half) {
#if JAX_THREEFRY_PARTITIONABLE
    U2 o = tf2x32(ka, kb, 0u, i);
    return o.a ^ o.b;
#else
    if (i < half) { return tf2x32(ka, kb, i, i + half).a; }
    else          { return tf2x32(ka, kb, i - half, i).b; }
#endif
}

__device__ __forceinline__ float group16_sum(float v) {
    v += __shfl_xor(v, 1);
    v += __shfl_xor(v, 2);
    v += __shfl_xor(v, 4);
    v += __shfl_xor(v, 8);
    return v;
}

// ---------------- Kernel 1: inverse L2 norms ----------------
__global__ __launch_bounds__(256) void inv_norm_kernel(const float* __restrict__ emb,
                                                       float* __restrict__ invn, int N) {
    const int tid = threadIdx.x;
    const int g = tid >> 4, sl = tid & 15;
    const int row = blockIdx.x * 16 + g;
    if (row >= N) return;
    float4 v = *reinterpret_cast<const float4*>(emb + (size_t)row * 64 + sl * 4);
    float ss = v.x * v.x + v.y * v.y + v.z * v.z + v.w * v.w;
    ss = group16_sum(ss);
    if (sl == 0) invn[row] = 1.0f / fmaxf(sqrtf(ss), 1e-12f);
}

// ---------------- Kernel 2: per-edge loss, per-block partial sums ----------------
__global__ __launch_bounds__(256) void edge_loss_kernel(
    const float* __restrict__ emb, const int* __restrict__ ei,
    const float* __restrict__ invn, float* __restrict__ partial,
    int E, uint32_t span, uint32_t mult, uint32_t half,
    uint32_t k1a, uint32_t k1b, uint32_t k2a, uint32_t k2b) {
    const int tid = threadIdx.x;
    const int g = tid >> 4;          // group (edge) within block
    const int sl = tid & 15;         // sublane within group
    const int lane = tid & 63;       // lane within wave
    const int e = blockIdx.x * 16 + g;

    float loss = 0.0f;
    if (e < E) {
        const int s = ei[e];
        const int d = ei[E + e];
        const float inv_s = invn[s];
        const float inv_d = invn[d];
        const float4 sv = *reinterpret_cast<const float4*>(emb + (size_t)s * 64 + sl * 4);
        const float4 dv = *reinterpret_cast<const float4*>(emb + (size_t)d * 64 + sl * 4);

        // negative index for slot sl (sublanes 0..9)
        int negidx = 0;
        if (sl < 10) {
            const int a = min(s, d);
            const int b = max(s, d);
            const uint32_t i = (uint32_t)e * 10u + (uint32_t)sl;
            uint32_t off = draw_bits(k2a, k2b, i, half) % span;  // lower bits
            if (mult != 0u) {
                uint32_t hi = draw_bits(k1a, k1b, i, half) % span;
                off = (hi * mult + off) % span;   // uint32 wrap == lax semantics
            }
            int r = (int)off;
            int r1 = r + (r >= a ? 1 : 0);                 // skip a
            negidx = r1 + (((a != b) && (r1 >= b)) ? 1 : 0); // skip b if distinct
        }

        // positive similarity
        float p = sv.x * dv.x + sv.y * dv.y + sv.z * dv.z + sv.w * dv.w;
        p = group16_sum(p);
        const float pos = p * inv_s * inv_d * 2.0f;  // /T, T=0.5

        float m = pos;
        float ns[10];
        #pragma unroll
        for (int k = 0; k < 10; ++k) {
            const int idx = __shfl(negidx, (lane & 48) | k);
            const float4 nv = *reinterpret_cast<const float4*>(emb + (size_t)idx * 64 + sl * 4);
            float q = sv.x * nv.x + sv.y * nv.y + sv.z * nv.z + sv.w * nv.w;
            q = group16_sum(q);
            const float nsim = q * inv_s * invn[idx] * 2.0f;
            ns[k] = nsim;
            m = fmaxf(m, nsim);
        }
        float ssum = expf(pos - m);
        #pragma unroll
        for (int k = 0; k < 10; ++k) ssum += expf(ns[k] - m);
        const float lse = m + logf(ssum);
        const float ratio = expf(pos - lse);
        loss = -logf(ratio + 1e-8f);
    }

    // block reduction: group leaders -> wave sum -> LDS -> partial[block]
    float v = (sl == 0) ? loss : 0.0f;
    v += __shfl_xor(v, 16);
    v += __shfl_xor(v, 32);
    __shared__ float sred[4];
    const int wid = tid >> 6;
    if (lane == 0) sred[wid] = v;
    __syncthreads();
    if (tid == 0) partial[blockIdx.x] = sred[0] + sred[1] + sred[2] + sred[3];
}

// ---------------- Kernel 3: deterministic final reduce (double) ----------------
__global__ __launch_bounds__(256) void finalize_kernel(const float* __restrict__ partial,
                                                       int n, float* __restrict__ out) {
    __shared__ double sd[256];
    double acc = 0.0;
    for (int i = threadIdx.x; i < n; i += 256) acc += (double)partial[i];
    sd[threadIdx.x] = acc;
    __syncthreads();
    for (int s = 128; s > 0; s >>= 1) {
        if (threadIdx.x < s) sd[threadIdx.x] += sd[threadIdx.x + s];
        __syncthreads();
    }
    if (threadIdx.x == 0) out[0] = (float)sd[0];
}

extern "C" void kernel_launch(void* const* d_in, const int* in_sizes, int n_in,
                              void* d_out, int out_size, void* d_ws, size_t ws_size,
                              hipStream_t stream) {
    const float* emb = (const float*)d_in[0];
    const int* ei = (const int*)d_in[1];
    const int N = in_sizes[0] / 64;   // 100000
    const int E = in_sizes[1] / 2;    // 400000
    const int K = 10;                  // K_NEG fixed by problem definition

    float* invn = (float*)d_ws;                 // N floats
    float* partial = invn + N;                  // nblk floats

    const int nblk_main = (E + 15) / 16;
    const int nblk_norm = (N + 15) / 16;

    const uint32_t span = (uint32_t)(N - 2);    // 99998
    const uint32_t m0 = 65536u % span;
    const uint32_t mult = (uint32_t)(m0 * m0) % span;  // wraps mod 2^32 like lax => 0 here
    const uint32_t half = (uint32_t)((E * K) / 2);     // only used by non-partitionable path

    inv_norm_kernel<<<nblk_norm, 256, 0, stream>>>(emb, invn, N);
    edge_loss_kernel<<<nblk_main, 256, 0, stream>>>(emb, ei, invn, partial,
                                                    E, span, mult, half,
                                                    KEY_HI.a, KEY_HI.b, KEY_LO.a, KEY_LO.b);
    finalize_kernel<<<1, 256, 0, stream>>>(partial, nblk_main, (float*)d_out);
}